// Round 6
// baseline (419.475 us; speedup 1.0000x reference)
//
#include <hip/hip_runtime.h>

// conv_transpose2d(x(4,256,128,128), w(256,256,4,4) block-diagonal, stride=2)
// -> out (4,256,258,258). Depthwise: off-diagonal w entries are exactly 0.0,
// so using only w[c][c] is bit-identical to the dense conv.
//
// R8 = x2-WORK SELF-CALIBRATION. Exactly the R6 kernel (e2e 340.7us), but
// the entire per-slice computation runs TWICE, rewriting identical values
// (bit-identical output, test still passes). An asm memory clobber between
// reps defeats dead-store elimination, so both passes' stores are issued.
// The e2e delta vs R6 directly measures one kernel pass (write-dominated),
// settling whether the kernel is ~70us (already at the mixed-stream HBM
// roofline; e2e dominated by harness poison fill + tiny reset dispatches)
// or ~170us (2 TB/s mystery, 100us still on the table). Grid/body otherwise
// untouched; reverts next round.

#define CCH   256
#define HIN   128
#define WIN   128
#define HOUT  258
#define WOUT  258
#define PAIRS 129            // cell-rows ci in [0,128]; out rows 2ci, 2ci+1
#define PERB  17             // row-pairs per band (8 bands: 7x17 + 1x10)

__global__ __launch_bounds__(256) void upconv2x_kernel(
    const float* __restrict__ x,
    const float* __restrict__ w,
    float* __restrict__ out)
{
    const int slice = blockIdx.y;             // n*CCH + c
    const int c = slice & (CCH - 1);

    // Uniform index -> scalar loads into SGPRs (no LDS, no sync)
    const float* __restrict__ wf = w + ((size_t)c * CCH + c) * 16;
    float f[16];
#pragma unroll
    for (int i = 0; i < 16; ++i) f[i] = wf[i];

    const int wave = threadIdx.x >> 6;
    const int lane = threadIdx.x & 63;

    const float* __restrict__ xs = x + (size_t)slice * (HIN * WIN);
    float* __restrict__ os = out + (size_t)slice * ((size_t)HOUT * WOUT);

#pragma unroll 1
    for (int rep = 0; rep < 2; ++rep) {
        for (int half = 0; half < 2; ++half) {
            const int band = half * 4 + wave;      // 0..7
            const int c0 = band * PERB;
            const int c1 = (c0 + PERB < PAIRS) ? (c0 + PERB) : PAIRS;

            // Registers for input rows at cols {2j-1, 2j, 2j+1}:
            //   p* = x[ci-1], c* = x[ci]
            float pm = 0.f, p0v = 0.f, p1v = 0.f;
            float cm = 0.f, c0v = 0.f, c1v = 0.f;
            if (c0 > 0) {                          // wave-uniform branch
                const float2 v = *(const float2*)(xs + (size_t)(c0 - 1) * WIN + 2 * lane);
                p0v = v.x; p1v = v.y;
                pm = __shfl_up(p1v, 1); if (lane == 0) pm = 0.f;
            }
            {   // c0 <= 119 < HIN always
                const float2 v = *(const float2*)(xs + (size_t)c0 * WIN + 2 * lane);
                c0v = v.x; c1v = v.y;
                cm = __shfl_up(c1v, 1); if (lane == 0) cm = 0.f;
            }

            float* __restrict__ pr = os + (size_t)(2 * c0) * WOUT + 4 * lane;

            for (int ci = c0; ci < c1; ++ci) {
                // prefetch next input row (wave-uniform condition)
                float nm = 0.f, n0v = 0.f, n1v = 0.f;
                if ((ci + 1 < c1) && (ci + 1 < HIN)) {
                    const float2 v = *(const float2*)(xs + (size_t)(ci + 1) * WIN + 2 * lane);
                    n0v = v.x; n1v = v.y;
                    nm = __shfl_up(n1v, 1); if (lane == 0) nm = 0.f;
                }

                // out[2ci][2cj+dw] = x[ci][cj]*f[dw] + x[ci][cj-1]*f[dw+2]
                //                  + x[ci-1][cj]*f[8+dw] + x[ci-1][cj-1]*f[10+dw]
                float4 r;
                r.x = c0v*f[0] + cm *f[2] + p0v*f[8]  + pm *f[10];
                r.y = c0v*f[1] + cm *f[3] + p0v*f[9]  + pm *f[11];
                r.z = c1v*f[0] + c0v*f[2] + p1v*f[8]  + p0v*f[10];
                r.w = c1v*f[1] + c0v*f[3] + p1v*f[9]  + p0v*f[11];
                *(float4*)pr = r;                        // dense 1024 B per wave
                if (lane == 63)                          // cols 256,257: m-terms only
                    *(float2*)(pr + 4) = make_float2(c1v*f[2] + p1v*f[10],
                                                     c1v*f[3] + p1v*f[11]);

                r.x = c0v*f[4] + cm *f[6] + p0v*f[12] + pm *f[14];
                r.y = c0v*f[5] + cm *f[7] + p0v*f[13] + pm *f[15];
                r.z = c1v*f[4] + c0v*f[6] + p1v*f[12] + p0v*f[14];
                r.w = c1v*f[5] + c0v*f[7] + p1v*f[13] + p0v*f[15];
                *(float4*)(pr + WOUT) = r;
                if (lane == 63)
                    *(float2*)(pr + WOUT + 4) = make_float2(c1v*f[6] + p1v*f[14],
                                                            c1v*f[7] + p1v*f[15]);

                // rotate rows: prev <- cur <- next
                pm = cm; p0v = c0v; p1v = c1v;
                cm = nm; c0v = n0v; c1v = n1v;
                pr += 2 * WOUT;
            }
        }
        // Defeat dead-store elimination of the first pass: compiler must
        // assume memory is read here, so both passes' stores are issued.
        asm volatile("" ::: "memory");
    }
}

extern "C" void kernel_launch(void* const* d_in, const int* in_sizes, int n_in,
                              void* d_out, int out_size, void* d_ws, size_t ws_size,
                              hipStream_t stream) {
    const float* x = (const float*)d_in[0];
    const float* w = (const float*)d_in[1];
    float* out = (float*)d_out;

    dim3 block(256);                 // 4 waves; 2 bands each (R6 config)
    dim3 grid(1, 4 * CCH);
    upconv2x_kernel<<<grid, block, 0, stream>>>(x, w, out);
}

// Round 8
// 341.389 us; speedup vs baseline: 1.2287x; 1.2287x over previous
//
#include <hip/hip_runtime.h>

// conv_transpose2d(x(4,256,128,128), w(256,256,4,4) block-diagonal, stride=2)
// -> out (4,256,258,258). Depthwise: off-diagonal w entries are exactly 0.0,
// so using only w[c][c] is bit-identical to the dense conv.
//
// R10 = resubmission of R9 (identical source; R9's bench was an infra
// failure). R9 itself was the restore of the best-measured kernel (R6,
// e2e 340.7us) after the R8 x2-work calibration settled attribution:
//   R6 (1x work) = 340.7us, R8 (2x work) = 419.5us -> one kernel pass ~79us,
//   i.e. ~4.3-4.9 TB/s effective for the 340 MB compulsory traffic. The
//   kernel is at/near the mixed-stream HBM roofline; the remaining ~270us of
//   e2e is harness cost (1.09GB poison fill ~180us + tiny reset dispatches).
//
// Structure: lane j of a wave owns output cols 4j..4j+3 of a full row; one
// wave store = dense contiguous 1024 B. Each wave marches down PERB row-pairs
// of one slice (2 bands serially), carrying rows x[ci-1], x[ci] in registers
// with a 1-row prefetch; left halo via __shfl_up. Filter w[c][c] in SGPRs;
// no LDS, no __syncthreads.

#define CCH   256
#define HIN   128
#define WIN   128
#define HOUT  258
#define WOUT  258
#define PAIRS 129            // cell-rows ci in [0,128]; out rows 2ci, 2ci+1
#define PERB  17             // row-pairs per band (8 bands: 7x17 + 1x10)

__global__ __launch_bounds__(256) void upconv2x_kernel(
    const float* __restrict__ x,
    const float* __restrict__ w,
    float* __restrict__ out)
{
    const int slice = blockIdx.y;             // n*CCH + c
    const int c = slice & (CCH - 1);

    // Uniform index -> scalar loads into SGPRs (no LDS, no sync)
    const float* __restrict__ wf = w + ((size_t)c * CCH + c) * 16;
    float f[16];
#pragma unroll
    for (int i = 0; i < 16; ++i) f[i] = wf[i];

    const int wave = threadIdx.x >> 6;
    const int lane = threadIdx.x & 63;

    const float* __restrict__ xs = x + (size_t)slice * (HIN * WIN);
    float* __restrict__ os = out + (size_t)slice * ((size_t)HOUT * WOUT);

    for (int half = 0; half < 2; ++half) {
        const int band = half * 4 + wave;          // 0..7
        const int c0 = band * PERB;
        const int c1 = (c0 + PERB < PAIRS) ? (c0 + PERB) : PAIRS;

        // Registers for input rows at cols {2j-1, 2j, 2j+1}:
        //   p* = x[ci-1], c* = x[ci]
        float pm = 0.f, p0v = 0.f, p1v = 0.f;
        float cm = 0.f, c0v = 0.f, c1v = 0.f;
        if (c0 > 0) {                              // wave-uniform branch
            const float2 v = *(const float2*)(xs + (size_t)(c0 - 1) * WIN + 2 * lane);
            p0v = v.x; p1v = v.y;
            pm = __shfl_up(p1v, 1); if (lane == 0) pm = 0.f;
        }
        {   // c0 <= 119 < HIN always
            const float2 v = *(const float2*)(xs + (size_t)c0 * WIN + 2 * lane);
            c0v = v.x; c1v = v.y;
            cm = __shfl_up(c1v, 1); if (lane == 0) cm = 0.f;
        }

        float* __restrict__ pr = os + (size_t)(2 * c0) * WOUT + 4 * lane;

        for (int ci = c0; ci < c1; ++ci) {
            // prefetch next input row (wave-uniform condition)
            float nm = 0.f, n0v = 0.f, n1v = 0.f;
            if ((ci + 1 < c1) && (ci + 1 < HIN)) {
                const float2 v = *(const float2*)(xs + (size_t)(ci + 1) * WIN + 2 * lane);
                n0v = v.x; n1v = v.y;
                nm = __shfl_up(n1v, 1); if (lane == 0) nm = 0.f;
            }

            // out[2ci][2cj+dw] = x[ci][cj]*f[dw] + x[ci][cj-1]*f[dw+2]
            //                  + x[ci-1][cj]*f[8+dw] + x[ci-1][cj-1]*f[10+dw]
            // lane j covers cj = 2j (cols 4j,4j+1) and cj = 2j+1 (cols 4j+2,4j+3)
            float4 r;
            r.x = c0v*f[0] + cm *f[2] + p0v*f[8]  + pm *f[10];
            r.y = c0v*f[1] + cm *f[3] + p0v*f[9]  + pm *f[11];
            r.z = c1v*f[0] + c0v*f[2] + p1v*f[8]  + p0v*f[10];
            r.w = c1v*f[1] + c0v*f[3] + p1v*f[9]  + p0v*f[11];
            *(float4*)pr = r;                        // dense 1024 B per wave
            if (lane == 63)                          // cols 256,257: m-terms only
                *(float2*)(pr + 4) = make_float2(c1v*f[2] + p1v*f[10],
                                                 c1v*f[3] + p1v*f[11]);

            r.x = c0v*f[4] + cm *f[6] + p0v*f[12] + pm *f[14];
            r.y = c0v*f[5] + cm *f[7] + p0v*f[13] + pm *f[15];
            r.z = c1v*f[4] + c0v*f[6] + p1v*f[12] + p0v*f[14];
            r.w = c1v*f[5] + c0v*f[7] + p1v*f[13] + p0v*f[15];
            *(float4*)(pr + WOUT) = r;
            if (lane == 63)
                *(float2*)(pr + WOUT + 4) = make_float2(c1v*f[6] + p1v*f[14],
                                                        c1v*f[7] + p1v*f[15]);

            // rotate rows: prev <- cur <- next
            pm = cm; p0v = c0v; p1v = c1v;
            cm = nm; c0v = n0v; c1v = n1v;
            pr += 2 * WOUT;
        }
    }
}

extern "C" void kernel_launch(void* const* d_in, const int* in_sizes, int n_in,
                              void* d_out, int out_size, void* d_ws, size_t ws_size,
                              hipStream_t stream) {
    const float* x = (const float*)d_in[0];
    const float* w = (const float*)d_in[1];
    float* out = (float*)d_out;

    dim3 block(256);                 // 4 waves; each does 2 bands serially
    dim3 grid(1, 4 * CCH);           // 1024 blocks
    upconv2x_kernel<<<grid, block, 0, stream>>>(x, w, out);
}